// Round 2
// 326.135 us; speedup vs baseline: 1.5033x; 1.5033x over previous
//
#include <hip/hip_runtime.h>
#include <cstdint>
#include <math.h>

// GREEN since r6. Best = r15 490us (swizzled unT4 b128). r13 (readlane) and
// r14 (all-reg U) PROVED: moving DS work to VALU loses; only deletions win.
// r16 bench was an INFRA FAILURE (container failed twice, no compile error,
// no profile) -> THIS ROUND r17 = resubmit of r16 unchanged (typo cleanup).
// r16/r17 experiment: delete HALF the dot-product VALU issue via
// v_pk_fma_f32. The two chains (a,b) are packed into 64-bit register pairs:
// h is ALREADY stored as float2{ha,hb} in LDS (perfect pk layout),
// accumulators become v2f {a,b}, and the shared U element is broadcast from
// the lo/hi half of an even-aligned U register pair via op_sel/op_sel_hi --
// zero extra v_movs. Per-half FMA order is k-ascending, IDENTICAL to r15 ->
// bit-identical decisions (absmax must stay 0.0).
// Measures an undocumented HW rate: if pk_fma_f32 is single-pass on the
// SIMD-32 f32 pipe -> dot issue halves (384->192 instr/step/wave, ~78% of
// VALU issue) -> predict ~360-400us. If double-pumped (f64 path) -> neutral.
// EMPIRICAL RULES: only __launch_bounds__(64,1) gives the full reg budget
// ((64,2)->128 cap, r8 disaster); allocator grants ~180 VGPR, 128-reg U is
// safe; OccupancyPercent counter is gfx94x fallback (untrustworthy).
// Locked-in: PRNG = partitionable threefry (key_t = tf((0,42),(0,t)); bits =
// o0^o1 of tf(key_t,(0,2s+cat))); f32 in/out; out = [4096*144][4096];
// decisions rounding-robust (6 arithmetic variants, bit-identical streams).

#define NSAMP 4096
#define NSTEP 144
#define HID 64
#define CPB 2            // chains per block (one wave)

typedef float v16f __attribute__((ext_vector_type(16)));
typedef float v4f  __attribute__((ext_vector_type(4)));
typedef float v2f  __attribute__((ext_vector_type(2)));

// ---- JAX threefry2x32 (20 rounds, key-inject every 4) ----
__device__ __forceinline__ void threefry2x32(uint32_t k0, uint32_t k1,
                                             uint32_t x0, uint32_t x1,
                                             uint32_t& o0, uint32_t& o1) {
  const uint32_t ks0 = k0, ks1 = k1, ks2 = k0 ^ k1 ^ 0x1BD11BDAu;
  x0 += ks0; x1 += ks1;
#define TF_ROUND(d) { x0 += x1; x1 = (x1 << (d)) | (x1 >> (32 - (d))); x1 ^= x0; }
  TF_ROUND(13) TF_ROUND(15) TF_ROUND(26) TF_ROUND(6)
  x0 += ks1; x1 += ks2 + 1u;
  TF_ROUND(17) TF_ROUND(29) TF_ROUND(16) TF_ROUND(24)
  x0 += ks2; x1 += ks0 + 2u;
  TF_ROUND(13) TF_ROUND(15) TF_ROUND(26) TF_ROUND(6)
  x0 += ks0; x1 += ks1 + 3u;
  TF_ROUND(17) TF_ROUND(29) TF_ROUND(16) TF_ROUND(24)
  x0 += ks1; x1 += ks2 + 4u;
  TF_ROUND(13) TF_ROUND(15) TF_ROUND(26) TF_ROUND(6)
  x0 += ks2; x1 += ks0 + 5u;
#undef TF_ROUND
  o0 = x0; o1 = x1;
}

// fast branch-free f32 transcendentals (raw v_exp_f32 / v_log_f32 / v_rcp_f32)
__device__ __forceinline__ float fsig(float x) {        // 1/(1+e^-x), stable
  return __builtin_amdgcn_rcpf(1.0f + __expf(-x));
}
__device__ __forceinline__ float ftanh(float x) {       // 1 - 2/(e^2x+1)
  const float e = __expf(2.0f * x);
  return 1.0f - 2.0f * __builtin_amdgcn_rcpf(e + 1.0f);
}

// Packed f32 FMA, chains (a,b) in (lo,hi). u-pair is an even-aligned register
// pair; LO variant broadcasts its low element to both halves, HI the high one.
// Non-volatile, register-only: scheduler remains free; deps via operands.
#define PKFMA_LO(acc, h2, up) \
  asm("v_pk_fma_f32 %0, %1, %2, %0 op_sel_hi:[1,0,1]" \
      : "+v"(acc) : "v"(h2), "v"(up));
#define PKFMA_HI(acc, h2, up) \
  asm("v_pk_fma_f32 %0, %1, %2, %0 op_sel:[0,1,0] op_sel_hi:[1,1,1]" \
      : "+v"(acc) : "v"(h2), "v"(up));

__global__ __launch_bounds__(64, 1) void vmc_kernel(
    const float* __restrict__ W, const float* __restrict__ U,
    const float* __restrict__ B, const float* __restrict__ Wd,
    const float* __restrict__ Bd, float* __restrict__ out) {
  const int j = threadIdx.x;           // hidden unit owned by this lane
  const int s_base = blockIdx.x * CPB; // first of 2 chains in this block

  __shared__ __align__(16) float2 hsh2[HID];      // h[unit] = {chain a, chain b}
  __shared__ __align__(16) float4 unT4[HID * 16]; // Un^T, XOR-swizzled chunks
  __shared__ uint2 kkeys[NSTEP];
  __shared__ float gsh[CPB * 2 * NSTEP];          // gumbels [c*288 + 2t + cat]

  // --- per-step keys: key_t = threefry((0,42),(0,t)) ---
#pragma unroll 1
  for (int t = j; t < NSTEP; t += HID) {
    uint32_t o0, o1;
    threefry2x32(0u, 42u, 0u, (uint32_t)t, o0, o1);
    kkeys[t].x = o0; kkeys[t].y = o1;
  }
  // --- stage Un^T: lane j owns row j (Un column j), chunk c = k/4,
  // swizzled index c^(j&15). Global reads coalesced across lanes. ---
#pragma unroll 4
  for (int c = 0; c < 16; ++c) {
    float4 v;
    v.x = U[(4*c + 0) * 192 + 128 + j];
    v.y = U[(4*c + 1) * 192 + 128 + j];
    v.z = U[(4*c + 2) * 192 + 128 + j];
    v.w = U[(4*c + 3) * 192 + 128 + j];
    unT4[j * 16 + (c ^ (j & 15))] = v;
  }
  hsh2[j] = float2{0.0f, 0.0f};
  __syncthreads();

  // --- gumbels: EXACT path kept (f64 libm, one-time): bits = o0^o1 of
  // tf(key_t,(0,2s+cat)); u = bitcast(bits>>9|0x3f800000)-1 clamped tiny ---
#pragma unroll 1
  for (int id = j; id < CPB * 2 * NSTEP; id += HID) {
    const int c = id / 288;
    const int idx = id - c * 288;
    const uint2 kt = kkeys[idx >> 1];
    const uint32_t i = 2u * (uint32_t)(s_base + c) + (uint32_t)(idx & 1);
    uint32_t o0, o1;
    threefry2x32(kt.x, kt.y, 0u, i, o0, o1);
    const uint32_t bits = o0 ^ o1;
    union { uint32_t u; float f; } cv; cv.u = (bits >> 9) | 0x3F800000u;
    float uf = cv.f - 1.0f;
    uf = fmaxf(uf, 1.17549435e-38f);
    const float inner = (float)log((double)uf);
    gsh[id] = -(float)log((double)(-inner));
  }
  __syncthreads();

  // --- Uz, Ur columns for unit j: register-resident (128 floats, proven) ---
  v16f uz0, uz1, uz2, uz3, ur0, ur1, ur2, ur3;
#define LOADB(v, r, off) \
  { _Pragma("unroll") for (int e = 0; e < 16; ++e) v[e] = U[((r)*16 + e)*192 + (off) + j]; }
  LOADB(uz0, 0, 0)   LOADB(uz1, 1, 0)   LOADB(uz2, 2, 0)   LOADB(uz3, 3, 0)
  LOADB(ur0, 0, 64)  LOADB(ur1, 1, 64)  LOADB(ur2, 2, 64)  LOADB(ur3, 3, 64)
#undef LOADB

  const float b1z = B[192 + j], b1r = B[256 + j], b1n = B[320 + j];
  const float b0z = B[j],       b0r = B[64 + j],  b0n = B[128 + j];
  const float xW0z = W[j]       + b0z, xW1z = W[192 + j] + b0z;
  const float xW0r = W[64 + j]  + b0r, xW1r = W[256 + j] + b0r;
  const float xW0n = W[128 + j] + b0n, xW1n = W[320 + j] + b0n;
  const float wdd = Wd[2*j + 1] - Wd[2*j];   // dense difference column
  const float bdd = Bd[1] - Bd[0];
  const int swz = j & 15;

  float ha = 0.0f, hb_ = 0.0f;
  float logPa = 0.0f, logPb = 0.0f;
  float axz = b0z, axr = b0r, axn = b0n;  // t=0: x=0 -> xm = b[0]
  float bxz = b0z, bxr = b0r, bxn = b0n;
  // loop-carried packed dot accumulators {chain a, chain b}; h_{-1}=0 -> 0
  v2f hz2 = {0.f, 0.f}, hr2 = {0.f, 0.f}, hn2 = {0.f, 0.f};

  for (int t = 0; t < NSTEP; ++t) {
    // ---- gates from the PREVIOUS iteration's dot (software pipeline) ----
    {
      const float az = axz + (hz2.x + b1z), ar = axr + (hr2.x + b1r);
      const float zz = fsig(az), rr = fsig(ar);
      const float hh = ftanh(axn + rr * (hn2.x + b1n));
      ha = zz * ha + (1.0f - zz) * hh;
    }
    {
      const float az = bxz + (hz2.y + b1z), ar = bxr + (hr2.y + b1r);
      const float zz = fsig(az), rr = fsig(ar);
      const float hh = ftanh(bxn + rr * (hn2.y + b1n));
      hb_ = zz * hb_ + (1.0f - zz) * hh;
    }
    hsh2[j] = float2{ha, hb_};   // single wave: LDS ops in program order

    // ---- dense: single difference-reduction per chain (r14-proven) ----
    float da = ha * wdd, db = hb_ * wdd;
#pragma unroll
    for (int m = 1; m < 64; m <<= 1) {
      da += __shfl_xor(da, m, 64);
      db += __shfl_xor(db, m, 64);
    }
    int sma, smb;
    {
      const float d = da + bdd;
      const float p1 = fsig(d), p0 = fsig(-d);
      const float lp0 = __logf(1e-10f + p0);
      const float lp1 = __logf(1e-10f + p1);
      const float g0 = gsh[2*t], g1 = gsh[2*t + 1];
      sma = (lp1 + g1) > (lp0 + g0);
      logPa += sma ? lp1 : lp0;
      axz = sma ? xW1z : xW0z;
      axr = sma ? xW1r : xW0r;
      axn = sma ? xW1n : xW0n;
    }
    {
      const float d = db + bdd;
      const float p1 = fsig(d), p0 = fsig(-d);
      const float lp0 = __logf(1e-10f + p0);
      const float lp1 = __logf(1e-10f + p1);
      const float g0 = gsh[288 + 2*t], g1 = gsh[288 + 2*t + 1];
      smb = (lp1 + g1) > (lp0 + g0);
      logPb += smb ? lp1 : lp0;
      bxz = smb ? xW1z : xW0z;
      bxr = smb ? xW1r : xW0r;
      bxn = smb ? xW1n : xW0n;
    }
    if (j == 0) {
      out[(s_base + 0) * NSTEP + t] = sma ? 1.0f : 0.0f;
      out[(s_base + 1) * NSTEP + t] = smb ? 1.0f : 0.0f;
    }

    // ---- dot for NEXT step: hm = h_t @ U, k-ascending per half, packed
    // {a,b}. h pairs come straight from LDS float2 layout; U element is
    // broadcast from an even-aligned pair via op_sel. Same values, same
    // per-half order as r15 -> bit-identical decisions. ----
    hz2 = v2f{0.f, 0.f}; hr2 = v2f{0.f, 0.f}; hn2 = v2f{0.f, 0.f};
#define DOTC(uzv, urv, blk, cc) \
    { const int c_ = (blk)*4 + (cc); \
      const v4f hA = *(const v4f*)&hsh2[c_*4]; \
      const v4f hB = *(const v4f*)&hsh2[c_*4 + 2]; \
      const v4f uv = *(const v4f*)&unT4[j*16 + (c_ ^ swz)]; \
      const v2f h0  = __builtin_shufflevector(hA, hA, 0, 1); \
      const v2f h1  = __builtin_shufflevector(hA, hA, 2, 3); \
      const v2f h2_ = __builtin_shufflevector(hB, hB, 0, 1); \
      const v2f h3  = __builtin_shufflevector(hB, hB, 2, 3); \
      const v2f uz01 = __builtin_shufflevector(uzv, uzv, (cc)*4 + 0, (cc)*4 + 1); \
      const v2f uz23 = __builtin_shufflevector(uzv, uzv, (cc)*4 + 2, (cc)*4 + 3); \
      const v2f ur01 = __builtin_shufflevector(urv, urv, (cc)*4 + 0, (cc)*4 + 1); \
      const v2f ur23 = __builtin_shufflevector(urv, urv, (cc)*4 + 2, (cc)*4 + 3); \
      const v2f un01 = __builtin_shufflevector(uv, uv, 0, 1); \
      const v2f un23 = __builtin_shufflevector(uv, uv, 2, 3); \
      PKFMA_LO(hz2, h0,  uz01) PKFMA_LO(hr2, h0,  ur01) PKFMA_LO(hn2, h0,  un01) \
      PKFMA_HI(hz2, h1,  uz01) PKFMA_HI(hr2, h1,  ur01) PKFMA_HI(hn2, h1,  un01) \
      PKFMA_LO(hz2, h2_, uz23) PKFMA_LO(hr2, h2_, ur23) PKFMA_LO(hn2, h2_, un23) \
      PKFMA_HI(hz2, h3,  uz23) PKFMA_HI(hr2, h3,  ur23) PKFMA_HI(hn2, h3,  un23) }
#define DOTBLK(uzv, urv, blk) \
    DOTC(uzv, urv, blk, 0) DOTC(uzv, urv, blk, 1) DOTC(uzv, urv, blk, 2) DOTC(uzv, urv, blk, 3)
    DOTBLK(uz0, ur0, 0)
    DOTBLK(uz1, ur1, 1)
    DOTBLK(uz2, ur2, 2)
    DOTBLK(uz3, ur3, 3)
#undef DOTBLK
#undef DOTC
  }

  if (j == 0) {
    *(float2*)&out[NSAMP * NSTEP + s_base] = float2{logPa, logPb};
  }
}

extern "C" void kernel_launch(void* const* d_in, const int* in_sizes, int n_in,
                              void* d_out, int out_size, void* d_ws, size_t ws_size,
                              hipStream_t stream) {
  // inputs (setup_inputs order): nsamples(1), W(2x192), U(64x192), b(2x192),
  // Wd(64x2), bd(2) — float32
  const float* W  = (const float*)d_in[1];
  const float* U  = (const float*)d_in[2];
  const float* B  = (const float*)d_in[3];
  const float* Wd = (const float*)d_in[4];
  const float* Bd = (const float*)d_in[5];
  vmc_kernel<<<dim3(NSAMP / CPB), dim3(HID), 0, stream>>>(W, U, B, Wd, Bd, (float*)d_out);
}

// Round 4
// 301.622 us; speedup vs baseline: 1.6255x; 1.0813x over previous
//
#include <hip/hip_runtime.h>
#include <cstdint>
#include <math.h>

// GREEN since r6. Ladder: r12 529 -> r15 490 (swizzled unT4 b128) -> r17 326
// (v_pk_fma_f32 PROVEN full-rate on gfx950: packed f32 = 2x FMA throughput;
// VGPR 132->104, VALUBusy 59->65%). r13 (readlane) / r14 (all-reg U at
// 132-VGPR base -> AGPR accvgpr chains, 838us) PROVED DS->VALU moves lose
// ONLY when register pressure forces AGPR chains.
// r18 failed to COMPILE (mov_dpp ctrl must be an immediate -> now a template
// param). THIS ROUND r19 = r18 resubmit:
//  (a) butterfly m=1,2,4,8 -> DPP (quad_perm 0xB1/0x4E, half_mirror 0x141,
//      mirror 0x140; valid: after m=1,2 partial sums are bitwise
//      quad-/8-uniform by IEEE add commutativity). m=16,32 stay __shfl_xor.
//      Same masks, same order, same adds -> bit-exact. Deletes 8/12 DS
//      round-trips from the decision-critical path.
//  (b) Un -> registers (un0..un3 v16f). pk freed the budget: 192 U-regs +
//      ~40 live ~= 235 <= 256 arch VGPRs (r14 was ~260+). Same values, same
//      FMA order. Deletes 16 per-lane ds_read_b128/step + 16KB LDS.
// Failure signature: dur >400us + VGPR anomaly = AGPR mode on (b); revert
// (b) only, keep (a).
// EMPIRICAL RULES: only __launch_bounds__(64,1) gives the full reg budget
// ((64,2)->128 cap, r8 disaster); OccupancyPercent counter is gfx94x
// fallback (untrustworthy). Occupancy is grid-capped at 2 waves/SIMD.
// Locked-in: PRNG = partitionable threefry (key_t = tf((0,42),(0,t)); bits =
// o0^o1 of tf(key_t,(0,2s+cat))); f32 in/out; out = [4096*144][4096];
// decisions rounding-robust (6 arithmetic variants, bit-identical streams).

#define NSAMP 4096
#define NSTEP 144
#define HID 64
#define CPB 2            // chains per block (one wave)

typedef float v16f __attribute__((ext_vector_type(16)));
typedef float v4f  __attribute__((ext_vector_type(4)));
typedef float v2f  __attribute__((ext_vector_type(2)));

// ---- JAX threefry2x32 (20 rounds, key-inject every 4) ----
__device__ __forceinline__ void threefry2x32(uint32_t k0, uint32_t k1,
                                             uint32_t x0, uint32_t x1,
                                             uint32_t& o0, uint32_t& o1) {
  const uint32_t ks0 = k0, ks1 = k1, ks2 = k0 ^ k1 ^ 0x1BD11BDAu;
  x0 += ks0; x1 += ks1;
#define TF_ROUND(d) { x0 += x1; x1 = (x1 << (d)) | (x1 >> (32 - (d))); x1 ^= x0; }
  TF_ROUND(13) TF_ROUND(15) TF_ROUND(26) TF_ROUND(6)
  x0 += ks1; x1 += ks2 + 1u;
  TF_ROUND(17) TF_ROUND(29) TF_ROUND(16) TF_ROUND(24)
  x0 += ks2; x1 += ks0 + 2u;
  TF_ROUND(13) TF_ROUND(15) TF_ROUND(26) TF_ROUND(6)
  x0 += ks0; x1 += ks1 + 3u;
  TF_ROUND(17) TF_ROUND(29) TF_ROUND(16) TF_ROUND(24)
  x0 += ks1; x1 += ks2 + 4u;
  TF_ROUND(13) TF_ROUND(15) TF_ROUND(26) TF_ROUND(6)
  x0 += ks2; x1 += ks0 + 5u;
#undef TF_ROUND
  o0 = x0; o1 = x1;
}

// fast branch-free f32 transcendentals (raw v_exp_f32 / v_log_f32 / v_rcp_f32)
__device__ __forceinline__ float fsig(float x) {        // 1/(1+e^-x), stable
  return __builtin_amdgcn_rcpf(1.0f + __expf(-x));
}
__device__ __forceinline__ float ftanh(float x) {       // 1 - 2/(e^2x+1)
  const float e = __expf(2.0f * x);
  return 1.0f - 2.0f * __builtin_amdgcn_rcpf(e + 1.0f);
}

// Packed f32 FMA, chains (a,b) in (lo,hi). u-pair is an even-aligned register
// pair; LO variant broadcasts its low element to both halves, HI the high one.
#define PKFMA_LO(acc, h2, up) \
  asm("v_pk_fma_f32 %0, %1, %2, %0 op_sel_hi:[1,0,1]" \
      : "+v"(acc) : "v"(h2), "v"(up));
#define PKFMA_HI(acc, h2, up) \
  asm("v_pk_fma_f32 %0, %1, %2, %0 op_sel:[0,1,0] op_sel_hi:[1,1,1]" \
      : "+v"(acc) : "v"(h2), "v"(up));

// DPP butterfly level: v += lane-swapped(v). ctrl is a template param so the
// builtin sees a constant expression (r18 compile fix). Patterns chosen so
// the swapped value is bitwise-identical to __shfl_xor(v, m) given the
// uniformity that holds at that butterfly level (see header comment).
template <int CTRL>
__device__ __forceinline__ float dpp_add(float v) {
  union { float f; int i; } c; c.f = v;
  union { int i; float f; } r;
  r.i = __builtin_amdgcn_mov_dpp(c.i, CTRL, 0xF, 0xF, true);
  return v + r.f;
}
#define DPP_XOR1 0xB1   // quad_perm(1,0,3,2)
#define DPP_XOR2 0x4E   // quad_perm(2,3,0,1)
#define DPP_XOR4 0x141  // row_half_mirror (quad-uniform => == xor4)
#define DPP_XOR8 0x140  // row_mirror (8-uniform => == xor8)

__global__ __launch_bounds__(64, 1) void vmc_kernel(
    const float* __restrict__ W, const float* __restrict__ U,
    const float* __restrict__ B, const float* __restrict__ Wd,
    const float* __restrict__ Bd, float* __restrict__ out) {
  const int j = threadIdx.x;           // hidden unit owned by this lane
  const int s_base = blockIdx.x * CPB; // first of 2 chains in this block

  __shared__ __align__(16) float2 hsh2[HID];      // h[unit] = {chain a, chain b}
  __shared__ uint2 kkeys[NSTEP];
  __shared__ float gsh[CPB * 2 * NSTEP];          // gumbels [c*288 + 2t + cat]

  // --- per-step keys: key_t = threefry((0,42),(0,t)) ---
#pragma unroll 1
  for (int t = j; t < NSTEP; t += HID) {
    uint32_t o0, o1;
    threefry2x32(0u, 42u, 0u, (uint32_t)t, o0, o1);
    kkeys[t].x = o0; kkeys[t].y = o1;
  }
  hsh2[j] = float2{0.0f, 0.0f};
  __syncthreads();

  // --- gumbels: EXACT path kept (f64 libm, one-time): bits = o0^o1 of
  // tf(key_t,(0,2s+cat)); u = bitcast(bits>>9|0x3f800000)-1 clamped tiny ---
#pragma unroll 1
  for (int id = j; id < CPB * 2 * NSTEP; id += HID) {
    const int c = id / 288;
    const int idx = id - c * 288;
    const uint2 kt = kkeys[idx >> 1];
    const uint32_t i = 2u * (uint32_t)(s_base + c) + (uint32_t)(idx & 1);
    uint32_t o0, o1;
    threefry2x32(kt.x, kt.y, 0u, i, o0, o1);
    const uint32_t bits = o0 ^ o1;
    union { uint32_t u; float f; } cv; cv.u = (bits >> 9) | 0x3F800000u;
    float uf = cv.f - 1.0f;
    uf = fmaxf(uf, 1.17549435e-38f);
    const float inner = (float)log((double)uf);
    gsh[id] = -(float)log((double)(-inner));
  }
  __syncthreads();

  // --- Uz, Ur, Un columns for unit j: ALL register-resident (192 floats).
  // pk freed the budget (r17: 104 VGPR); 192 + ~40 live <= 256 arch. ---
  v16f uz0, uz1, uz2, uz3, ur0, ur1, ur2, ur3, un0, un1, un2, un3;
#define LOADB(v, r, off) \
  { _Pragma("unroll") for (int e = 0; e < 16; ++e) v[e] = U[((r)*16 + e)*192 + (off) + j]; }
  LOADB(uz0, 0, 0)    LOADB(uz1, 1, 0)    LOADB(uz2, 2, 0)    LOADB(uz3, 3, 0)
  LOADB(ur0, 0, 64)   LOADB(ur1, 1, 64)   LOADB(ur2, 2, 64)   LOADB(ur3, 3, 64)
  LOADB(un0, 0, 128)  LOADB(un1, 1, 128)  LOADB(un2, 2, 128)  LOADB(un3, 3, 128)
#undef LOADB

  const float b1z = B[192 + j], b1r = B[256 + j], b1n = B[320 + j];
  const float b0z = B[j],       b0r = B[64 + j],  b0n = B[128 + j];
  const float xW0z = W[j]       + b0z, xW1z = W[192 + j] + b0z;
  const float xW0r = W[64 + j]  + b0r, xW1r = W[256 + j] + b0r;
  const float xW0n = W[128 + j] + b0n, xW1n = W[320 + j] + b0n;
  const float wdd = Wd[2*j + 1] - Wd[2*j];   // dense difference column
  const float bdd = Bd[1] - Bd[0];

  float ha = 0.0f, hb_ = 0.0f;
  float logPa = 0.0f, logPb = 0.0f;
  float axz = b0z, axr = b0r, axn = b0n;  // t=0: x=0 -> xm = b[0]
  float bxz = b0z, bxr = b0r, bxn = b0n;
  // loop-carried packed dot accumulators {chain a, chain b}; h_{-1}=0 -> 0
  v2f hz2 = {0.f, 0.f}, hr2 = {0.f, 0.f}, hn2 = {0.f, 0.f};

  for (int t = 0; t < NSTEP; ++t) {
    // ---- gates from the PREVIOUS iteration's dot (software pipeline) ----
    {
      const float az = axz + (hz2.x + b1z), ar = axr + (hr2.x + b1r);
      const float zz = fsig(az), rr = fsig(ar);
      const float hh = ftanh(axn + rr * (hn2.x + b1n));
      ha = zz * ha + (1.0f - zz) * hh;
    }
    {
      const float az = bxz + (hz2.y + b1z), ar = bxr + (hr2.y + b1r);
      const float zz = fsig(az), rr = fsig(ar);
      const float hh = ftanh(bxn + rr * (hn2.y + b1n));
      hb_ = zz * hb_ + (1.0f - zz) * hh;
    }
    hsh2[j] = float2{ha, hb_};   // single wave: LDS ops in program order

    // ---- dense: difference-reduction, butterfly m=1..32. Levels 1-8 via
    // DPP VALU (bit-exact, see header), 16/32 via shfl. ----
    float da = ha * wdd, db = hb_ * wdd;
    da = dpp_add<DPP_XOR1>(da); db = dpp_add<DPP_XOR1>(db);
    da = dpp_add<DPP_XOR2>(da); db = dpp_add<DPP_XOR2>(db);
    da = dpp_add<DPP_XOR4>(da); db = dpp_add<DPP_XOR4>(db);
    da = dpp_add<DPP_XOR8>(da); db = dpp_add<DPP_XOR8>(db);
    da += __shfl_xor(da, 16, 64); db += __shfl_xor(db, 16, 64);
    da += __shfl_xor(da, 32, 64); db += __shfl_xor(db, 32, 64);

    int sma, smb;
    {
      const float d = da + bdd;
      const float p1 = fsig(d), p0 = fsig(-d);
      const float lp0 = __logf(1e-10f + p0);
      const float lp1 = __logf(1e-10f + p1);
      const float g0 = gsh[2*t], g1 = gsh[2*t + 1];
      sma = (lp1 + g1) > (lp0 + g0);
      logPa += sma ? lp1 : lp0;
      axz = sma ? xW1z : xW0z;
      axr = sma ? xW1r : xW0r;
      axn = sma ? xW1n : xW0n;
    }
    {
      const float d = db + bdd;
      const float p1 = fsig(d), p0 = fsig(-d);
      const float lp0 = __logf(1e-10f + p0);
      const float lp1 = __logf(1e-10f + p1);
      const float g0 = gsh[288 + 2*t], g1 = gsh[288 + 2*t + 1];
      smb = (lp1 + g1) > (lp0 + g0);
      logPb += smb ? lp1 : lp0;
      bxz = smb ? xW1z : xW0z;
      bxr = smb ? xW1r : xW0r;
      bxn = smb ? xW1n : xW0n;
    }
    if (j == 0) {
      out[(s_base + 0) * NSTEP + t] = sma ? 1.0f : 0.0f;
      out[(s_base + 1) * NSTEP + t] = smb ? 1.0f : 0.0f;
    }

    // ---- dot for NEXT step: hm = h_t @ U, k-ascending per half, packed
    // {a,b}. h pairs from LDS float2 broadcast; ALL U operands from regs.
    // Same values, same per-half order as r17 -> bit-identical decisions. ----
    hz2 = v2f{0.f, 0.f}; hr2 = v2f{0.f, 0.f}; hn2 = v2f{0.f, 0.f};
#define DOTC(uzv, urv, unv, blk, cc) \
    { const int c_ = (blk)*4 + (cc); \
      const v4f hA = *(const v4f*)&hsh2[c_*4]; \
      const v4f hB = *(const v4f*)&hsh2[c_*4 + 2]; \
      const v2f h0  = __builtin_shufflevector(hA, hA, 0, 1); \
      const v2f h1  = __builtin_shufflevector(hA, hA, 2, 3); \
      const v2f h2_ = __builtin_shufflevector(hB, hB, 0, 1); \
      const v2f h3  = __builtin_shufflevector(hB, hB, 2, 3); \
      const v2f uz01 = __builtin_shufflevector(uzv, uzv, (cc)*4 + 0, (cc)*4 + 1); \
      const v2f uz23 = __builtin_shufflevector(uzv, uzv, (cc)*4 + 2, (cc)*4 + 3); \
      const v2f ur01 = __builtin_shufflevector(urv, urv, (cc)*4 + 0, (cc)*4 + 1); \
      const v2f ur23 = __builtin_shufflevector(urv, urv, (cc)*4 + 2, (cc)*4 + 3); \
      const v2f un01 = __builtin_shufflevector(unv, unv, (cc)*4 + 0, (cc)*4 + 1); \
      const v2f un23 = __builtin_shufflevector(unv, unv, (cc)*4 + 2, (cc)*4 + 3); \
      PKFMA_LO(hz2, h0,  uz01) PKFMA_LO(hr2, h0,  ur01) PKFMA_LO(hn2, h0,  un01) \
      PKFMA_HI(hz2, h1,  uz01) PKFMA_HI(hr2, h1,  ur01) PKFMA_HI(hn2, h1,  un01) \
      PKFMA_LO(hz2, h2_, uz23) PKFMA_LO(hr2, h2_, ur23) PKFMA_LO(hn2, h2_, un23) \
      PKFMA_HI(hz2, h3,  uz23) PKFMA_HI(hr2, h3,  ur23) PKFMA_HI(hn2, h3,  un23) }
#define DOTBLK(uzv, urv, unv, blk) \
    DOTC(uzv, urv, unv, blk, 0) DOTC(uzv, urv, unv, blk, 1) \
    DOTC(uzv, urv, unv, blk, 2) DOTC(uzv, urv, unv, blk, 3)
    DOTBLK(uz0, ur0, un0, 0)
    DOTBLK(uz1, ur1, un1, 1)
    DOTBLK(uz2, ur2, un2, 2)
    DOTBLK(uz3, ur3, un3, 3)
#undef DOTBLK
#undef DOTC
  }

  if (j == 0) {
    *(float2*)&out[NSAMP * NSTEP + s_base] = float2{logPa, logPb};
  }
}

extern "C" void kernel_launch(void* const* d_in, const int* in_sizes, int n_in,
                              void* d_out, int out_size, void* d_ws, size_t ws_size,
                              hipStream_t stream) {
  // inputs (setup_inputs order): nsamples(1), W(2x192), U(64x192), b(2x192),
  // Wd(64x2), bd(2) — float32
  const float* W  = (const float*)d_in[1];
  const float* U  = (const float*)d_in[2];
  const float* B  = (const float*)d_in[3];
  const float* Wd = (const float*)d_in[4];
  const float* Bd = (const float*)d_in[5];
  vmc_kernel<<<dim3(NSAMP / CPB), dim3(HID), 0, stream>>>(W, U, B, Wd, Bd, (float*)d_out);
}